// Round 1
// baseline (224.963 us; speedup 1.0000x reference)
//
#include <hip/hip_runtime.h>

// Problem constants (from reference): B=64, H=W=512, 256 zones.
#define NZ   256
#define NB   64
#define NPIX (512 * 512)

// Monotonic float->unsigned encoding: preserves total order, enc(NaN-ish)=small.
// enc never returns 0 for any real float (only for bits 0xFFFFFFFF = NaN).
__device__ __forceinline__ unsigned enc(float f) {
    unsigned b = __float_as_uint(f);
    return b ^ ((b & 0x80000000u) ? 0xFFFFFFFFu : 0x80000000u);
}
__device__ __forceinline__ float dec(unsigned u) {
    unsigned b = (u & 0x80000000u) ? (u ^ 0x80000000u) : ~u;
    return __uint_as_float(b);
}

// Pass 1: per-batch segmented max. Each block: 4096 consecutive pixels of one
// batch (256 threads x 16 elems via 4x float4). LDS pre-reduction -> <=256
// global atomics per block.
__global__ __launch_bounds__(256) void segmax_kernel(
        const float* __restrict__ inp, const int* __restrict__ zones,
        unsigned* __restrict__ segmax) {
    __shared__ unsigned smax[NZ];
    const int t = threadIdx.x;
    smax[t] = 0u;  // blockDim == NZ == 256
    __syncthreads();

    const int blocksPerBatch = NPIX / (256 * 16);  // 64
    const int batch = blockIdx.x / blocksPerBatch;
    const int chunk = blockIdx.x % blocksPerBatch;
    const long base = (long)batch * NPIX + (long)chunk * (256 * 16);
    const float4* in4 = (const float4*)(inp + base);
    const int4*   z4  = (const int4*)(zones + base);

#pragma unroll
    for (int it = 0; it < 4; ++it) {
        float4 v = in4[it * 256 + t];
        int4   z = z4[it * 256 + t];
        atomicMax(&smax[z.x], enc(v.x));
        atomicMax(&smax[z.y], enc(v.y));
        atomicMax(&smax[z.z], enc(v.z));
        atomicMax(&smax[z.w], enc(v.w));
    }
    __syncthreads();

    unsigned m = smax[t];
    if (m) atomicMax(&segmax[batch * NZ + t], m);  // m==0 -> zone untouched here
}

// Pass 2: mask = (x == segmax[zone]), int32 0/1; block-reduced count ->
// atomicAdd into the final output element.
__global__ __launch_bounds__(256) void mask_kernel(
        const float* __restrict__ inp, const int* __restrict__ zones,
        const unsigned* __restrict__ segmax,
        int* __restrict__ mask, int* __restrict__ count) {
    __shared__ float smax[NZ];
    __shared__ int bsum;
    const int t = threadIdx.x;

    const int blocksPerBatch = NPIX / (256 * 4);  // 256
    const int batch = blockIdx.x / blocksPerBatch;
    const int chunk = blockIdx.x % blocksPerBatch;

    smax[t] = dec(segmax[batch * NZ + t]);  // empty zone: dec(0)=NaN, matches nothing
    if (t == 0) bsum = 0;
    __syncthreads();

    const long base = (long)batch * NPIX + (long)chunk * (256 * 4);
    float4 v = ((const float4*)(inp + base))[t];
    int4   z = ((const int4*)(zones + base))[t];

    int4 m;
    m.x = (v.x == smax[z.x]) ? 1 : 0;
    m.y = (v.y == smax[z.y]) ? 1 : 0;
    m.z = (v.z == smax[z.z]) ? 1 : 0;
    m.w = (v.w == smax[z.w]) ? 1 : 0;
    ((int4*)(mask + base))[t] = m;

    int c = m.x + m.y + m.z + m.w;
#pragma unroll
    for (int off = 32; off; off >>= 1) c += __shfl_down(c, off);
    if ((t & 63) == 0) atomicAdd(&bsum, c);
    __syncthreads();
    if (t == 0) atomicAdd(count, bsum);
}

extern "C" void kernel_launch(void* const* d_in, const int* in_sizes, int n_in,
                              void* d_out, int out_size, void* d_ws, size_t ws_size,
                              hipStream_t stream) {
    const float* inp   = (const float*)d_in[0];
    const int*   zones = (const int*)d_in[1];
    int*         out   = (int*)d_out;          // [B*NPIX] mask + [1] n_centers, int32
    unsigned*    segmx = (unsigned*)d_ws;      // B*NZ encoded maxima

    const long nmask = (long)NB * NPIX;        // == out_size - 1

    // Deterministic init each call (harness does not re-poison between replays).
    hipMemsetAsync(d_ws, 0, (size_t)NB * NZ * sizeof(unsigned), stream);
    hipMemsetAsync(out + nmask, 0, sizeof(int), stream);

    segmax_kernel<<<NB * (NPIX / 4096), 256, 0, stream>>>(inp, zones, segmx);
    mask_kernel<<<NB * (NPIX / 1024), 256, 0, stream>>>(inp, zones, segmx, out, out + nmask);
}

// Round 2
// 59.232 us; speedup vs baseline: 3.7980x; 3.7980x over previous
//
#include <hip/hip_runtime.h>

// Problem constants (from reference): B=64, H=W=512, 256 zones.
#define NZ   256
#define NB   64
#define NPIX (512 * 512)

// Monotonic float->unsigned encoding: preserves total order.
// enc returns 0 only for bits 0xFFFFFFFF (a NaN) -> safe "empty" sentinel.
__device__ __forceinline__ unsigned enc(float f) {
    unsigned b = __float_as_uint(f);
    return b ^ ((b & 0x80000000u) ? 0xFFFFFFFFu : 0x80000000u);
}
__device__ __forceinline__ float dec(unsigned u) {
    unsigned b = (u & 0x80000000u) ? (u ^ 0x80000000u) : ~u;
    return __uint_as_float(b);
}

// Pass 1: per-batch segmented max. Each block: 4096 consecutive pixels of one
// batch (256 threads x 16 elems via 4x float4). LDS pre-reduction -> <=256
// global atomics per block (scattered across B*NZ table -> no hot line).
__global__ __launch_bounds__(256) void segmax_kernel(
        const float* __restrict__ inp, const int* __restrict__ zones,
        unsigned* __restrict__ segmax) {
    __shared__ unsigned smax[NZ];
    const int t = threadIdx.x;
    smax[t] = 0u;  // blockDim == NZ == 256
    __syncthreads();

    const int blocksPerBatch = NPIX / (256 * 16);  // 64
    const int batch = blockIdx.x / blocksPerBatch;
    const int chunk = blockIdx.x % blocksPerBatch;
    const long base = (long)batch * NPIX + (long)chunk * (256 * 16);
    const float4* in4 = (const float4*)(inp + base);
    const int4*   z4  = (const int4*)(zones + base);

#pragma unroll
    for (int it = 0; it < 4; ++it) {
        float4 v = in4[it * 256 + t];
        int4   z = z4[it * 256 + t];
        atomicMax(&smax[z.x], enc(v.x));
        atomicMax(&smax[z.y], enc(v.y));
        atomicMax(&smax[z.z], enc(v.z));
        atomicMax(&smax[z.w], enc(v.w));
    }
    __syncthreads();

    unsigned m = smax[t];
    if (m) atomicMax(&segmax[batch * NZ + t], m);  // m==0 -> zone untouched here
}

// Pass 2: mask = (x == segmax[zone]) as int32 0/1; per-block partial count
// written to its own slot (NO contended global atomic — that was 192us in R1).
__global__ __launch_bounds__(256) void mask_kernel(
        const float* __restrict__ inp, const int* __restrict__ zones,
        const unsigned* __restrict__ segmax,
        int* __restrict__ mask, int* __restrict__ partial) {
    __shared__ float smax[NZ];
    __shared__ int wsum[4];
    const int t = threadIdx.x;

    const int blocksPerBatch = NPIX / (256 * 16);  // 64
    const int batch = blockIdx.x / blocksPerBatch;
    const int chunk = blockIdx.x % blocksPerBatch;

    smax[t] = dec(segmax[batch * NZ + t]);  // empty zone: dec(0)=NaN, matches nothing
    __syncthreads();

    const long base = (long)batch * NPIX + (long)chunk * (256 * 16);
    const float4* in4 = (const float4*)(inp + base);
    const int4*   z4  = (const int4*)(zones + base);
    int4* m4 = (int4*)(mask + base);

    int c = 0;
#pragma unroll
    for (int it = 0; it < 4; ++it) {
        float4 v = in4[it * 256 + t];
        int4   z = z4[it * 256 + t];
        int4 m;
        m.x = (v.x == smax[z.x]) ? 1 : 0;
        m.y = (v.y == smax[z.y]) ? 1 : 0;
        m.z = (v.z == smax[z.z]) ? 1 : 0;
        m.w = (v.w == smax[z.w]) ? 1 : 0;
        m4[it * 256 + t] = m;
        c += m.x + m.y + m.z + m.w;
    }

#pragma unroll
    for (int off = 32; off; off >>= 1) c += __shfl_down(c, off);
    if ((t & 63) == 0) wsum[t >> 6] = c;
    __syncthreads();
    if (t == 0) partial[blockIdx.x] = wsum[0] + wsum[1] + wsum[2] + wsum[3];
}

// Pass 3: single tiny block sums the 4096 partials into the output counter.
__global__ __launch_bounds__(256) void count_kernel(
        const int* __restrict__ partial, int n, int* __restrict__ count) {
    __shared__ int wsum[4];
    const int t = threadIdx.x;
    int c = 0;
    for (int i = t; i < n; i += 256) c += partial[i];
#pragma unroll
    for (int off = 32; off; off >>= 1) c += __shfl_down(c, off);
    if ((t & 63) == 0) wsum[t >> 6] = c;
    __syncthreads();
    if (t == 0) *count = wsum[0] + wsum[1] + wsum[2] + wsum[3];
}

extern "C" void kernel_launch(void* const* d_in, const int* in_sizes, int n_in,
                              void* d_out, int out_size, void* d_ws, size_t ws_size,
                              hipStream_t stream) {
    const float* inp   = (const float*)d_in[0];
    const int*   zones = (const int*)d_in[1];
    int*         out   = (int*)d_out;            // [B*NPIX] mask + [1] n_centers, int32
    unsigned*    segmx = (unsigned*)d_ws;        // B*NZ encoded maxima (64 KB)
    int*         partial = (int*)((char*)d_ws + NB * NZ * sizeof(unsigned));

    const long nmask = (long)NB * NPIX;          // == out_size - 1
    const int nblocks = NB * (NPIX / 4096);      // 4096

    // Deterministic init each call (harness does not re-poison between replays).
    hipMemsetAsync(d_ws, 0, (size_t)NB * NZ * sizeof(unsigned), stream);

    segmax_kernel<<<nblocks, 256, 0, stream>>>(inp, zones, segmx);
    mask_kernel<<<nblocks, 256, 0, stream>>>(inp, zones, segmx, out, partial);
    count_kernel<<<1, 256, 0, stream>>>(partial, nblocks, out + nmask);
}

// Round 3
// 56.010 us; speedup vs baseline: 4.0165x; 1.0575x over previous
//
#include <hip/hip_runtime.h>

// Problem constants (from reference): B=64, H=W=512, 256 zones.
#define NZ    256
#define NB    64
#define NPIX  (512 * 512)

// Pass-1 geometry: 32 elems/thread -> 2048 blocks, 1 KB partial table each.
#define EPT1  32
#define CHUNK1 (256 * EPT1)        // 8192 px per block
#define BPB1  (NPIX / CHUNK1)      // 32 blocks per batch
#define NBLK1 (NB * BPB1)          // 2048

// Pass-3 geometry: 16 elems/thread -> 4096 blocks (matches R2's 13us config).
#define CHUNK3 (256 * 16)
#define BPB3  (NPIX / CHUNK3)      // 64
#define NBLK3 (NB * BPB3)          // 4096

// Monotonic float->unsigned encoding: preserves total order.
// enc()==0 only for bits 0xFFFFFFFF (a NaN) -> safe "empty" sentinel; dec(0)=NaN.
__device__ __forceinline__ unsigned enc(float f) {
    unsigned b = __float_as_uint(f);
    return b ^ ((b & 0x80000000u) ? 0xFFFFFFFFu : 0x80000000u);
}
__device__ __forceinline__ float dec(unsigned u) {
    unsigned b = (u & 0x80000000u) ? (u ^ 0x80000000u) : ~u;
    return __uint_as_float(b);
}

// Pass 1: per-block LDS segmax over 8192 consecutive pixels; store the whole
// 256-entry table to a PRIVATE slot (no global atomics -> no hot-line tail).
// Loads are explicitly register-staged 8-deep and pinned with sched_barrier
// so the compiler cannot collapse them into a load->wait->atomic chain
// (R2 evidence: VGPR_Count=12 meant <=2 loads in flight, 3.9% VALUBusy).
__global__ __launch_bounds__(256) void segmax_part(
        const float* __restrict__ inp, const int* __restrict__ zones,
        unsigned* __restrict__ part) {
    __shared__ unsigned smax[NZ];
    const int t = threadIdx.x;
    smax[t] = 0u;  // blockDim == NZ == 256
    __syncthreads();

    const int batch = blockIdx.x / BPB1;
    const int chunk = blockIdx.x % BPB1;
    const long base = (long)batch * NPIX + (long)chunk * CHUNK1;
    const float4* in4 = (const float4*)(inp + base);
    const int4*   z4  = (const int4*)(zones + base);

#pragma unroll
    for (int h = 0; h < EPT1 / 16; ++h) {
        float4 v[4];
        int4   z[4];
#pragma unroll
        for (int i = 0; i < 4; ++i) {
            const int idx = (h * 4 + i) * 256 + t;
            v[i] = in4[idx];
            z[i] = z4[idx];
        }
        __builtin_amdgcn_sched_barrier(0);  // all 8 loads issue before atomics
#pragma unroll
        for (int i = 0; i < 4; ++i) {
            atomicMax(&smax[z[i].x], enc(v[i].x));
            atomicMax(&smax[z[i].y], enc(v[i].y));
            atomicMax(&smax[z[i].z], enc(v[i].z));
            atomicMax(&smax[z[i].w], enc(v[i].w));
        }
    }
    __syncthreads();
    part[(long)blockIdx.x * NZ + t] = smax[t];  // coalesced 1 KB store
}

// Pass 2: one block per batch; thread t max-combines zone t over the batch's
// 32 chunk tables (stride-NZ reads are coalesced across threads) and stores
// the DECODED float (empty zone -> dec(0)=NaN, matches no pixel).
__global__ __launch_bounds__(256) void segmax_reduce(
        const unsigned* __restrict__ part, float* __restrict__ segf) {
    const int t = threadIdx.x;
    const int batch = blockIdx.x;
    const unsigned* p = part + (long)batch * BPB1 * NZ;
    unsigned m = 0u;
#pragma unroll 8
    for (int c = 0; c < BPB1; ++c) m = max(m, p[c * NZ + t]);
    segf[batch * NZ + t] = dec(m);
}

// Pass 3: mask = (x == segmax[zone]) as int32 0/1; per-block partial count to
// a private slot (contended global atomicAdd was the 192us R1 bug).
__global__ __launch_bounds__(256) void mask_kernel(
        const float* __restrict__ inp, const int* __restrict__ zones,
        const float* __restrict__ segf,
        int* __restrict__ mask, int* __restrict__ partial) {
    __shared__ float smax[NZ];
    __shared__ int wsum[4];
    const int t = threadIdx.x;

    const int batch = blockIdx.x / BPB3;
    const int chunk = blockIdx.x % BPB3;

    smax[t] = segf[batch * NZ + t];
    __syncthreads();

    const long base = (long)batch * NPIX + (long)chunk * CHUNK3;
    const float4* in4 = (const float4*)(inp + base);
    const int4*   z4  = (const int4*)(zones + base);
    int4* m4 = (int4*)(mask + base);

    int c = 0;
#pragma unroll
    for (int it = 0; it < 4; ++it) {
        float4 v = in4[it * 256 + t];
        int4   z = z4[it * 256 + t];
        int4 m;
        m.x = (v.x == smax[z.x]) ? 1 : 0;
        m.y = (v.y == smax[z.y]) ? 1 : 0;
        m.z = (v.z == smax[z.z]) ? 1 : 0;
        m.w = (v.w == smax[z.w]) ? 1 : 0;
        m4[it * 256 + t] = m;
        c += m.x + m.y + m.z + m.w;
    }

#pragma unroll
    for (int off = 32; off; off >>= 1) c += __shfl_down(c, off);
    if ((t & 63) == 0) wsum[t >> 6] = c;
    __syncthreads();
    if (t == 0) partial[blockIdx.x] = wsum[0] + wsum[1] + wsum[2] + wsum[3];
}

// Pass 4: single block sums the 4096 partials into the output counter.
__global__ __launch_bounds__(256) void count_kernel(
        const int* __restrict__ partial, int n, int* __restrict__ count) {
    __shared__ int wsum[4];
    const int t = threadIdx.x;
    int c = 0;
    for (int i = t; i < n; i += 256) c += partial[i];
#pragma unroll
    for (int off = 32; off; off >>= 1) c += __shfl_down(c, off);
    if ((t & 63) == 0) wsum[t >> 6] = c;
    __syncthreads();
    if (t == 0) *count = wsum[0] + wsum[1] + wsum[2] + wsum[3];
}

extern "C" void kernel_launch(void* const* d_in, const int* in_sizes, int n_in,
                              void* d_out, int out_size, void* d_ws, size_t ws_size,
                              hipStream_t stream) {
    const float* inp   = (const float*)d_in[0];
    const int*   zones = (const int*)d_in[1];
    int*         out   = (int*)d_out;   // [B*NPIX] mask + [1] n_centers, int32

    // Workspace layout (all fully overwritten every call -> no memset needed,
    // deterministic under graph replay):
    //   part   : NBLK1*NZ u32 = 2 MB
    //   segf   : NB*NZ   f32  = 64 KB
    //   partial: NBLK3   i32  = 16 KB
    unsigned* part    = (unsigned*)d_ws;
    float*    segf    = (float*)((char*)d_ws + (size_t)NBLK1 * NZ * 4);
    int*      partial = (int*)((char*)d_ws + (size_t)NBLK1 * NZ * 4 + (size_t)NB * NZ * 4);

    const long nmask = (long)NB * NPIX;  // == out_size - 1

    segmax_part  <<<NBLK1, 256, 0, stream>>>(inp, zones, part);
    segmax_reduce<<<NB,    256, 0, stream>>>(part, segf);
    mask_kernel  <<<NBLK3, 256, 0, stream>>>(inp, zones, segf, out, partial);
    count_kernel <<<1,     256, 0, stream>>>(partial, NBLK3, out + nmask);
}